// Round 8
// baseline (636.631 us; speedup 1.0000x reference)
//
#include <hip/hip_runtime.h>
#include <hip/hip_bf16.h>
#include <math.h>

// Problem constants (fixed by reference)
#define B_ 2
#define S_ 2048
#define D_ 1024
#define M_ (B_*S_)      // 4096 rows
#define CTXLD 3072      // fused ctx row stride: [short | medium | long]

typedef _Float16 half8_t __attribute__((ext_vector_type(8)));
typedef _Float16 half4_t __attribute__((ext_vector_type(4)));
typedef float    f32x4  __attribute__((ext_vector_type(4)));

// async global->LDS: per-lane global addr; HW scatters lane i to (uniform LDS base) + i*16B
#define GL2LDS(g, l) __builtin_amdgcn_global_load_lds( \
    (const __attribute__((address_space(1))) void*)(uintptr_t)(g), \
    (__attribute__((address_space(3))) void*)(l), 16, 0, 0)

// Softmax scales folded into Q at QKV-epilogue time (r7):
// long dk=64: (1/8)*log2e = 0.18033688 ; short/medium dk=128: (1/sqrt(128))*log2e
#define QSC_L  0.18033688011112f
#define QSC_SM 0.12751744707f

// ---------------------------------------------------------------------------
// Batched fp16-MFMA GEMM: C = A @ W^T + bias. BK=64 chunk-major.
// 128xNB tile (NB in {128,64}), 4 waves. batch dim selects {b0,b1,b2}.
// MODE 0: C fp32 + bias. MODE 1: C fp16 + bias.
// MODE 2: QKV split (cols<2048 -> qk fp16 ldc, Q cols (<1024) pre-scaled by
//         softmax scale*log2e; cols>=2048 -> vT transposed).
// MODE 3: C fp16, no bias (Weff prep).
// NB=64 for small-N dispatches (outproj N=1024 was 256 blocks = 1/CU).
// ---------------------------------------------------------------------------
struct GemmBatch {
    const _Float16* A;
    const _Float16* W;
    const float*    bias;
    void*           C;
    void*           C2;
};

template<int MODE, int NB>
__global__ __launch_bounds__(256) void gemm_f16(
    GemmBatch b0, GemmBatch b1, GemmBatch b2, int lda, int ldw, int ldc, int K)
{
    constexpr int NT = NB / 32;          // per-wave n-subtiles
    __shared__ __align__(16) _Float16 As[2*128*32];
    __shared__ __align__(16) _Float16 Bs[2*NB*32];

    const GemmBatch G = (blockIdx.z == 0) ? b0 : ((blockIdx.z == 1) ? b1 : b2);

    const int t = threadIdx.x, lane = t & 63, w = t >> 6;
    const int bm = blockIdx.x * 128, bn = blockIdx.y * NB;
    const int wm = (w >> 1) * 64, wn = (w & 1) * (NB/2);
    const int fr = lane & 15, q8 = (lane >> 4) * 8;
    const int srow = lane >> 2, scol = (lane & 3) * 8;

    f32x4 acc[4][NT] = {};

    const _Float16* Ab = G.A + (size_t)(bm + w*32 + srow) * lda + scol;
    const _Float16* Wb = G.W + (size_t)(bn + w*(NB/4) + srow) * ldw + scol;

    for (int k0 = 0; k0 < K; k0 += 64) {
        __syncthreads();
        #pragma unroll
        for (int kc = 0; kc < 2; kc++) {
            #pragma unroll
            for (int ii = 0; ii < 2; ii++)
                GL2LDS(Ab + (size_t)(ii*16)*lda + k0 + kc*32,
                       As + kc*4096 + w*1024 + ii*512);
            #pragma unroll
            for (int ii = 0; ii < NB/64; ii++)
                GL2LDS(Wb + (size_t)(ii*16)*ldw + k0 + kc*32,
                       Bs + kc*NB*32 + w*(NB/4)*32 + ii*512);
        }
        __syncthreads();
        #pragma unroll
        for (int kc = 0; kc < 2; kc++) {
            half8_t af[4], bf[NT];
            #pragma unroll
            for (int mt = 0; mt < 4; mt++)
                af[mt] = *(const half8_t*)&As[kc*4096 + (wm + mt*16 + fr)*32 + q8];
            #pragma unroll
            for (int nt = 0; nt < NT; nt++)
                bf[nt] = *(const half8_t*)&Bs[kc*NB*32 + (wn + nt*16 + fr)*32 + q8];
            #pragma unroll
            for (int mt = 0; mt < 4; mt++)
                #pragma unroll
                for (int nt = 0; nt < NT; nt++)
                    acc[mt][nt] = __builtin_amdgcn_mfma_f32_16x16x32_f16(
                        af[mt], bf[nt], acc[mt][nt], 0, 0, 0);
        }
    }

    const int cl = lane & 15;
    const int rq = (lane >> 4) * 4;

    if (MODE == 2 && bn >= 2048) {
        #pragma unroll
        for (int mt = 0; mt < 4; mt++) {
            int row0 = bm + wm + mt*16 + rq;
            #pragma unroll
            for (int nt = 0; nt < NT; nt++) {
                int gcol = bn + wn + nt*16 + cl;
                float bv = G.bias[gcol];
                half4_t hv = {(_Float16)(acc[mt][nt][0] + bv),
                              (_Float16)(acc[mt][nt][1] + bv),
                              (_Float16)(acc[mt][nt][2] + bv),
                              (_Float16)(acc[mt][nt][3] + bv)};
                *(half4_t*)((_Float16*)G.C2 + (size_t)(gcol - 2048) * M_ + row0) = hv;
            }
        }
        return;
    }

    // Q pre-scale (MODE 2, cols < 1024): batch z=2 is long (dk=64).
    const float qsc = (MODE == 2 && bn < 1024)
                      ? ((blockIdx.z == 2) ? QSC_L : QSC_SM) : 1.0f;

    #pragma unroll
    for (int mt = 0; mt < 4; mt++) {
        #pragma unroll
        for (int r = 0; r < 4; r++) {
            size_t grow = (size_t)(bm + wm + mt*16 + rq + r);
            #pragma unroll
            for (int nt = 0; nt < NT; nt++) {
                int gcol = bn + wn + nt*16 + cl;
                float v = acc[mt][nt][r] + ((MODE == 3) ? 0.f : G.bias[gcol]);
                if (MODE == 2) v *= qsc;
                if (MODE == 0)
                    ((float*)G.C)[grow * ldc + gcol] = v;
                else
                    ((_Float16*)G.C)[grow * ldc + gcol] = (_Float16)v;
            }
        }
    }
}

// ---------------------------------------------------------------------------
// Fused fp32 -> fp16 cast (5 tensors: x, w_in x3, w_comb).
// ---------------------------------------------------------------------------
struct CastArgs {
    const float* s[5];
    _Float16*    d[5];
    int          nb[5];
};

__global__ __launch_bounds__(256) void cast_all(CastArgs a)
{
    int off = blockIdx.x;
    int seg = 0;
    while (seg < 4 && off >= a.nb[seg]) { off -= a.nb[seg]; seg++; }
    int i = off * 256 + threadIdx.x;
    float4 v = ((const float4*)a.s[seg])[i];
    half4_t h = {(_Float16)v.x, (_Float16)v.y, (_Float16)v.z, (_Float16)v.w};
    ((half4_t*)a.d[seg])[i] = h;
}

// ---------------------------------------------------------------------------
// Transposing cast for wo_* : in fp32 [1024 d][1024 e] -> out fp16 [e][d].
// ---------------------------------------------------------------------------
__global__ __launch_bounds__(256) void transpose_cast_wo(
    const float* s0, const float* s1, const float* s2,
    _Float16* d0, _Float16* d1, _Float16* d2)
{
    __shared__ float T[64][68];
    const float* src = blockIdx.z == 0 ? s0 : (blockIdx.z == 1 ? s1 : s2);
    _Float16*    dst = blockIdx.z == 0 ? d0 : (blockIdx.z == 1 ? d1 : d2);
    const int db = blockIdx.x * 64;
    const int eb = blockIdx.y * 64;
    const int r = threadIdx.x >> 4;
    const int c = (threadIdx.x & 15) * 4;

    #pragma unroll
    for (int rr = 0; rr < 4; rr++) {
        float4 v = *(const float4*)&src[(size_t)(db + rr*16 + r)*1024 + eb + c];
        T[rr*16 + r][c+0] = v.x; T[rr*16 + r][c+1] = v.y;
        T[rr*16 + r][c+2] = v.z; T[rr*16 + r][c+3] = v.w;
    }
    __syncthreads();
    #pragma unroll
    for (int rr = 0; rr < 4; rr++) {
        int e = rr*16 + r;
        half4_t hv = {(_Float16)T[c+0][e], (_Float16)T[c+1][e],
                      (_Float16)T[c+2][e], (_Float16)T[c+3][e]};
        *(half4_t*)&dst[(size_t)(eb + e)*1024 + db + c] = hv;
    }
}

// ---------------------------------------------------------------------------
// beff[n] = b_comb[n] + sum_d bo_s[d] Wc[n][d] + bo_m[d] Wc[n][1024+d] + bo_l[d] Wc[n][2048+d]
// ---------------------------------------------------------------------------
__global__ __launch_bounds__(256) void beff_kernel(
    const float* __restrict__ w_comb, const float* __restrict__ b_comb,
    const float* __restrict__ bo_s, const float* __restrict__ bo_m,
    const float* __restrict__ bo_l, float* __restrict__ beff)
{
    __shared__ float red[4];
    const int n = blockIdx.x, t = threadIdx.x;
    float s = 0.f;
    for (int d = t; d < 1024; d += 256)
        s += w_comb[(size_t)n*3072 + d]        * bo_s[d]
           + w_comb[(size_t)n*3072 + 1024 + d] * bo_m[d]
           + w_comb[(size_t)n*3072 + 2048 + d] * bo_l[d];
    #pragma unroll
    for (int m = 32; m >= 1; m >>= 1) s += __shfl_xor(s, m);
    if ((t & 63) == 0) red[t >> 6] = s;
    __syncthreads();
    if (t == 0) beff[n] = b_comb[n] + red[0] + red[1] + red[2] + red[3];
}

// ---------------------------------------------------------------------------
// Flash attention body — r7: 8 waves / 512 threads / 128 q-rows per block.
// K/V staging per round unchanged but feeds 2x MFMA -> staging traffic,
// barrier count and stage-addr VALU all halve per unit work. LDS 43KB ->
// 3 blocks/CU = 24 waves (up from 16). Single-buffered (r4 dbuf regressed);
// no setprio (r5 regressed).
// LDS partition (halfs): Ks [0, DK*BJ) | Vs [DK*BJ, 2*DK*BJ) | Ps 8*16*40.
// T2 swizzle (r2): XOR 16B slot with (row>>1)&3 via pre-swizzled global
// source + swizzled read (BANK_CONFLICT 2.2e7 -> 4.9e6).
// Q is PRE-SCALED by softmax-scale*log2e at QKV epilogue -> exp2f(st) direct.
// ---------------------------------------------------------------------------
template<int DK, int BJ, bool LOUT>
__device__ __forceinline__ void flash_body(
    _Float16* lds, float* Lw,
    const _Float16* __restrict__ qk, const _Float16* __restrict__ vT,
    _Float16* __restrict__ ctx, float* __restrict__ lout,
    int window, int b, int h, int qblk, int H)
{
    constexpr int KS  = DK / 32;     // k-chunks
    constexpr int DT  = DK / 16;     // PV d-tiles
    constexpr int JT  = BJ / 16;     // j-subtiles per round
    constexpr int JC  = BJ / 32;     // j-chunks per round (PV kc count)
    constexpr int LDP = 40;
    constexpr int KRB = BJ / 16;     // K row-blocks (16 rows each)
    constexpr int VRB = DK / 16;     // V row-blocks

    _Float16* Ks = lds;
    _Float16* Vs = lds + DK*BJ;
    _Float16* Ps = lds + 2*DK*BJ;

    const int t = threadIdx.x, lane = t & 63, w = t >> 6;   // w in 0..7
    const int fr = lane & 15, g = lane >> 4, k8 = g * 8;
    // swizzled LDS fragment slot: slot g holds global chunk g^((row>>1)&3)
    const int k8s = (g ^ ((fr >> 1) & 3)) * 8;
    const int blkQ = qblk * 128;
    const int qlo  = blkQ + w * 16;

    _Float16* PsW = Ps + w * 16 * LDP;
    const int srow = lane >> 2;
    // stage-side inverse swizzle of the global source chunk
    const int ssw  = ((lane & 3) ^ ((srow >> 1) & 3)) * 8;

    half8_t qf[KS];
    #pragma unroll
    for (int kk = 0; kk < KS; kk++)
        qf[kk] = *(const half8_t*)&qk[(size_t)(b*S_ + qlo + fr)*2048 + h*DK + kk*32 + k8];

    f32x4 O[DT] = {};
    float lsum = 0.f;

    for (int j0 = 0; j0 < S_; j0 += BJ) {
        if (window >= 0 && j0 + BJ - 1 < blkQ - window) continue;
        __syncthreads();

        // stage K: 16 units (KS x KRB), wave w does units 2w, 2w+1
        #pragma unroll
        for (int i = 0; i < 2; i++) {
            int u = w*2 + i;
            int kk = u / KRB, rb = u % KRB;
            GL2LDS(&qk[(size_t)(b*S_ + j0 + rb*16 + srow)*2048
                       + 1024 + h*DK + kk*32 + ssw],
                   &Ks[kk*BJ*32 + rb*512]);
        }
        // stage vT: 16 units (JC x VRB), wave w does units 2w, 2w+1
        #pragma unroll
        for (int i = 0; i < 2; i++) {
            int u = w*2 + i;
            int jc = u / VRB, rb = u % VRB;
            GL2LDS(&vT[(size_t)(h*DK + rb*16 + srow)*M_
                       + b*S_ + j0 + jc*32 + ssw],
                   &Vs[jc*DK*32 + rb*512]);
        }
        __syncthreads();

        f32x4 st[JT];
        #pragma unroll
        for (int jt = 0; jt < JT; jt++) {
            f32x4 s = {};
            #pragma unroll
            for (int kk = 0; kk < KS; kk++) {
                half8_t kf = *(const half8_t*)&Ks[kk*BJ*32 + (jt*16 + fr)*32 + k8s];
                s = __builtin_amdgcn_mfma_f32_16x16x32_f16(kf, qf[kk], s, 0, 0, 0);
            }
            st[jt] = s;
        }

        const bool full = (window < 0) || (j0 >= qlo + 15 - window);
        #pragma unroll
        for (int kc = 0; kc < JC; kc++) {
            #pragma unroll
            for (int jh = 0; jh < 2; jh++) {
                int jt = kc*2 + jh;
                float p[4];
                #pragma unroll
                for (int r = 0; r < 4; r++) {
                    float pv = exp2f(st[jt][r]);
                    if (!full) {
                        int jg = j0 + jt*16 + g*4 + r;
                        if (jg < (qlo + fr) - window) pv = 0.f;
                    }
                    p[r] = pv;
                    lsum += pv;
                }
                half4_t ph = {(_Float16)p[0], (_Float16)p[1],
                              (_Float16)p[2], (_Float16)p[3]};
                *(half4_t*)&PsW[fr*LDP + jh*16 + g*4] = ph;
            }
            // same-wave DS ordering: write -> read -> next overwrite is safe
            half8_t pf = *(const half8_t*)&PsW[fr*LDP + k8];
            #pragma unroll
            for (int dt = 0; dt < DT; dt++) {
                half8_t vf = *(const half8_t*)&Vs[kc*DK*32 + (dt*16 + fr)*32 + k8s];
                O[dt] = __builtin_amdgcn_mfma_f32_16x16x32_f16(pf, vf, O[dt], 0, 0, 0);
            }
        }
    }

    lsum += __shfl_xor(lsum, 16);
    lsum += __shfl_xor(lsum, 32);
    if (g == 0) Lw[w*16 + fr] = lsum;
    float linv[4];
    #pragma unroll
    for (int r = 0; r < 4; r++)
        linv[r] = 1.f / Lw[w*16 + g*4 + r];

    if (LOUT && g == 0)
        lout[(size_t)(b*H + h)*S_ + qlo + fr] = lsum;

    #pragma unroll
    for (int r = 0; r < 4; r++) {
        _Float16* cp = ctx + (size_t)(b*S_ + qlo + g*4 + r)*CTXLD + h*DK;
        #pragma unroll
        for (int dt = 0; dt < DT; dt++)
            cp[dt*16 + fr] = (_Float16)(O[dt][r] * linv[r]);
    }
}

// ---------------------------------------------------------------------------
// Mega flash: 1024 blocks x 512 threads (128 q-rows each).
// T1 XCD remap: bid = (hw&7)*128 + hw>>3 (bijective, 1024 = 8*128).
// Group = 16 consecutive bids sharing one (branch,b,h) K/V panel.
// Groups alternate long/short-medium -> every XCD gets 4 long + 4 s/m
// groups = identical round counts (perfect balance).
// ---------------------------------------------------------------------------
__global__ __launch_bounds__(512, 6) void flash_mega(
    const _Float16* __restrict__ qk_s, const _Float16* __restrict__ qk_m,
    const _Float16* __restrict__ qk_l,
    const _Float16* __restrict__ vT_s, const _Float16* __restrict__ vT_m,
    const _Float16* __restrict__ vT_l,
    _Float16* __restrict__ ctxall, float* __restrict__ lbuf)
{
    __shared__ __align__(16) _Float16 lds[21504];
    __shared__ float Lw[128];

    const int hwb = blockIdx.x;
    const int bid = (hwb & 7) * 128 + (hwb >> 3);
    const int grp = bid >> 4, q = bid & 15;
    if (!(grp & 1)) {
        int lg = grp >> 1;              // 0..31
        int b = lg >> 4, h = lg & 15;
        flash_body<64, 128, true>(lds, Lw, qk_l, vT_l, ctxall + 2048, lbuf,
                                  -1, b, h, q, 16);
    } else {
        int sg = grp >> 1;              // 0..31
        int z = sg >> 3;                // 0..3 = branch*2 + batch
        int br = z >> 1, b = z & 1, h = sg & 7;
        flash_body<128, 64, false>(lds, Lw, br ? qk_m : qk_s, br ? vT_m : vT_s,
                                   ctxall + (br ? 1024 : 0), nullptr,
                                   br ? 30 : 10, b, h, q, 8);
    }
}

// ---------------------------------------------------------------------------
// Head-averaged long-branch attention probabilities (2 heads per barrier).
// Same T2 swizzle as flash_body. Q pre-scaled -> no c1 multiply.
// ---------------------------------------------------------------------------
__global__ __launch_bounds__(256, 4) void attn_mean3(
    const _Float16* __restrict__ qk,
    const float* __restrict__ lbuf,
    float* __restrict__ attn)
{
    __shared__ __align__(16) _Float16 Ks[2 * 2 * 128 * 32];

    const int t = threadIdx.x, lane = t & 63, w = t >> 6;
    const int fr = lane & 15, g = lane >> 4, k8 = g * 8;
    const int k8s = (g ^ ((fr >> 1) & 3)) * 8;
    const int j0 = blockIdx.x * 128;
    const int irow = blockIdx.y * 64 + w * 16;
    const int b = blockIdx.z;
    const int srow = lane >> 2;
    const int ssw  = ((lane & 3) ^ ((srow >> 1) & 3)) * 8;

    f32x4 acc[8] = {};

    for (int hp = 0; hp < 16; hp += 2) {
        __syncthreads();
        #pragma unroll
        for (int hh = 0; hh < 2; hh++)
            #pragma unroll
            for (int kk = 0; kk < 2; kk++)
                #pragma unroll
                for (int ii = 0; ii < 2; ii++)
                    GL2LDS(&qk[(size_t)(b*S_ + j0 + w*32 + ii*16 + srow)*2048
                               + 1024 + (hp+hh)*64 + kk*32 + ssw],
                           &Ks[hh*8192 + kk*4096 + w*1024 + ii*512]);
        __syncthreads();

        #pragma unroll
        for (int hh = 0; hh < 2; hh++) {
            const int h = hp + hh;
            half8_t af[2];
            #pragma unroll
            for (int kk = 0; kk < 2; kk++)
                af[kk] = *(const half8_t*)
                    &qk[(size_t)(b*S_ + irow + fr)*2048 + h*64 + kk*32 + k8];

            float lg[4];
            #pragma unroll
            for (int r = 0; r < 4; r++)
                lg[r] = __log2f(lbuf[(size_t)(b*16 + h)*S_ + irow + g*4 + r]) + 4.0f;

            #pragma unroll
            for (int nt = 0; nt < 8; nt++) {
                f32x4 s = {};
                #pragma unroll
                for (int kk = 0; kk < 2; kk++) {
                    half8_t bf = *(const half8_t*)
                        &Ks[hh*8192 + kk*4096 + (nt*16 + fr)*32 + k8s];
                    s = __builtin_amdgcn_mfma_f32_16x16x32_f16(af[kk], bf, s, 0, 0, 0);
                }
                #pragma unroll
                for (int r = 0; r < 4; r++)
                    acc[nt][r] += exp2f(s[r] - lg[r]);
            }
        }
    }

    #pragma unroll
    for (int r = 0; r < 4; r++) {
        float* p = attn + (size_t)(b*S_ + irow + g*4 + r)*S_ + j0;
        #pragma unroll
        for (int nt = 0; nt < 8; nt++)
            p[nt*16 + fr] = acc[nt][r];
    }
}

// ---------------------------------------------------------------------------
// Residual + LayerNorm
// ---------------------------------------------------------------------------
__global__ __launch_bounds__(256) void ln_residual(
    const float* __restrict__ pre, const float* __restrict__ x,
    const float* __restrict__ gamma, const float* __restrict__ beta,
    float* __restrict__ out)
{
    __shared__ float redS[4], redQ[4];
    const int row = blockIdx.x;
    const int t = threadIdx.x;
    size_t base = (size_t)row * D_ + t * 4;

    float4 v  = *(const float4*)(pre + base);
    float4 xv = *(const float4*)(x + base);
    v.x += xv.x; v.y += xv.y; v.z += xv.z; v.w += xv.w;

    float s = v.x + v.y + v.z + v.w;
    float q = v.x*v.x + v.y*v.y + v.z*v.z + v.w*v.w;
    #pragma unroll
    for (int m = 32; m >= 1; m >>= 1) {
        s += __shfl_xor(s, m);
        q += __shfl_xor(q, m);
    }
    int wave = t >> 6;
    if ((t & 63) == 0) { redS[wave] = s; redQ[wave] = q; }
    __syncthreads();
    s = redS[0] + redS[1] + redS[2] + redS[3];
    q = redQ[0] + redQ[1] + redQ[2] + redQ[3];

    float mean = s * (1.f / D_);
    float var  = q * (1.f / D_) - mean * mean;
    float rstd = rsqrtf(var + 1e-5f);

    float4 g  = *(const float4*)(gamma + t * 4);
    float4 be = *(const float4*)(beta + t * 4);
    float4 o;
    o.x = (v.x - mean) * rstd * g.x + be.x;
    o.y = (v.y - mean) * rstd * g.y + be.y;
    o.z = (v.z - mean) * rstd * g.z + be.z;
    o.w = (v.w - mean) * rstd * g.w + be.w;
    *(float4*)(out + base) = o;
}

// ---------------------------------------------------------------------------
extern "C" void kernel_launch(void* const* d_in, const int* in_sizes, int n_in,
                              void* d_out, int out_size, void* d_ws, size_t ws_size,
                              hipStream_t stream)
{
    (void)in_sizes; (void)n_in; (void)out_size; (void)ws_size;
    const float* x      = (const float*)d_in[0];
    const float* w_in_s = (const float*)d_in[1];
    const float* b_in_s = (const float*)d_in[2];
    const float* wo_s   = (const float*)d_in[3];
    const float* bo_s   = (const float*)d_in[4];
    const float* w_in_m = (const float*)d_in[5];
    const float* b_in_m = (const float*)d_in[6];
    const float* wo_m   = (const float*)d_in[7];
    const float* bo_m   = (const float*)d_in[8];
    const float* w_in_l = (const float*)d_in[9];
    const float* b_in_l = (const float*)d_in[10];
    const float* wo_l   = (const float*)d_in[11];
    const float* bo_l   = (const float*)d_in[12];
    const float* w_comb = (const float*)d_in[13];
    const float* b_comb = (const float*)d_in[14];
    const float* gamma  = (const float*)d_in[15];
    const float* beta   = (const float*)d_in[16];

    float* out    = (float*)d_out;                 // [B,S,D]
    float* attn_o = out + (size_t)M_ * D_;         // [B,S,S]

    // Workspace (byte offsets; total ~132.3 MB <= proven-available 134.5 MB).
    // Alias lifetimes (stream order):
    //   w_comb_h+woT_s [18,26)MB dead after weff gemm -> vT_l (qkv_all writes it after)
    //   qk_m dead after flash_mega -> pre (fused gemm output)
    char* W = (char*)d_ws;
    _Float16* w_in_s_h = (_Float16*)(W);                 //  6MB
    _Float16* w_in_m_h = (_Float16*)(W + 6291456);       //  6MB
    _Float16* w_in_l_h = (_Float16*)(W + 12582912);      //  6MB
    _Float16* w_comb_h = (_Float16*)(W + 18874368);      //  6MB (-> vT_l)
    _Float16* woT_s    = (_Float16*)(W + 25165824);      //  2MB (-> vT_l tail)
    _Float16* woT_m    = (_Float16*)(W + 27262976);      //  2MB
    _Float16* woT_l    = (_Float16*)(W + 29360128);      //  2MB
    _Float16* weff     = (_Float16*)(W + 31457280);      //  6MB
    _Float16* qk_s     = (_Float16*)(W + 37748736);      // 16MB
    _Float16* qk_m     = (_Float16*)(W + 54525952);      // 16MB (-> pre fp32)
    _Float16* qk_l     = (_Float16*)(W + 71303168);      // 16MB
    _Float16* vT_s     = (_Float16*)(W + 88080384);      //  8MB
    _Float16* vT_m     = (_Float16*)(W + 96468992);      //  8MB
    _Float16* ctxall   = (_Float16*)(W + 104857600);     // 24MB [4096][3072]
    _Float16* x_h      = (_Float16*)(W + 130023424);     //  8MB
    float*    lbuf     = (float*)   (W + 138412032);     // 256KB
    float*    beff     = (float*)   (W + 138674432);     //  4KB
    _Float16* vT_l     = w_comb_h;                       // 8MB alias (see above)
    float*    pre      = (float*)qk_m;

    dim3 blk(256);
    GemmBatch nil = { nullptr, nullptr, nullptr, nullptr, nullptr };

    // ---- casts: x, w_in x3, w_comb ----
    CastArgs ca;
    ca.s[0]=x;      ca.d[0]=x_h;      ca.nb[0]=4096;
    ca.s[1]=w_in_s; ca.d[1]=w_in_s_h; ca.nb[1]=3072;
    ca.s[2]=w_in_m; ca.d[2]=w_in_m_h; ca.nb[2]=3072;
    ca.s[3]=w_in_l; ca.d[3]=w_in_l_h; ca.nb[3]=3072;
    ca.s[4]=w_comb; ca.d[4]=w_comb_h; ca.nb[4]=3072;
    cast_all<<<dim3(16384), blk, 0, stream>>>(ca);

    // ---- transpose-cast wo_* -> woT_* ----
    transpose_cast_wo<<<dim3(16, 16, 3), blk, 0, stream>>>(
        wo_s, wo_m, wo_l, woT_s, woT_m, woT_l);

    // ---- Weff_b = Wc_b @ wo_b (fp16, no bias); NB=64 -> 384 blocks ----
    GemmBatch we0 = { w_comb_h + 0,    woT_s, nullptr, weff + 0,    nullptr };
    GemmBatch we1 = { w_comb_h + 1024, woT_m, nullptr, weff + 1024, nullptr };
    GemmBatch we2 = { w_comb_h + 2048, woT_l, nullptr, weff + 2048, nullptr };
    gemm_f16<3, 64><<<dim3(8, 16, 3), blk, 0, stream>>>(we0, we1, we2, 3072, 1024, 3072, 1024);

    // ---- beff = b_comb + Wc . bo_cat ----
    beff_kernel<<<dim3(1024), blk, 0, stream>>>(w_comb, b_comb, bo_s, bo_m, bo_l, beff);

    // ---- all three QKV projections in one dispatch (w_comb_h now dead -> vT_l) ----
    GemmBatch qs = { x_h, w_in_s_h, b_in_s, qk_s, vT_s };
    GemmBatch qm = { x_h, w_in_m_h, b_in_m, qk_m, vT_m };
    GemmBatch ql = { x_h, w_in_l_h, b_in_l, qk_l, vT_l };
    gemm_f16<2, 128><<<dim3(M_/128, 3072/128, 3), blk, 0, stream>>>(qs, qm, ql, D_, D_, 2048, D_);

    // ---- mega flash: 1024 x 512-thread blocks ----
    flash_mega<<<dim3(1024), dim3(512), 0, stream>>>(
        qk_s, qk_m, qk_l, vT_s, vT_m, vT_l, ctxall, lbuf);

    // ---- head-averaged probabilities ----
    attn_mean3<<<dim3(S_/128, S_/64, B_), blk, 0, stream>>>(qk_l, lbuf, attn_o);

    // ---- fused (outproj+combine): pre = ctxall @ weff^T + beff ----
    // NB=64 -> grid 32x16 = 512 blocks = 2/CU
    GemmBatch fb = { ctxall, weff, beff, pre, nullptr };
    gemm_f16<0, 64><<<dim3(M_/128, 1024/64, 1), blk, 0, stream>>>(fb, nil, nil, 3072, 3072, D_, 3072);

    // ---- residual LayerNorm ----
    ln_residual<<<dim3(M_), blk, 0, stream>>>(pre, x, gamma, beta, out);
}

// Round 9
// 527.470 us; speedup vs baseline: 1.2070x; 1.2070x over previous
//
#include <hip/hip_runtime.h>
#include <hip/hip_bf16.h>
#include <math.h>

// Problem constants (fixed by reference)
#define B_ 2
#define S_ 2048
#define D_ 1024
#define M_ (B_*S_)      // 4096 rows
#define CTXLD 3072      // fused ctx row stride: [short | medium | long]

typedef _Float16 half8_t __attribute__((ext_vector_type(8)));
typedef _Float16 half4_t __attribute__((ext_vector_type(4)));
typedef float    f32x4  __attribute__((ext_vector_type(4)));

// async global->LDS: per-lane global addr; HW scatters lane i to (uniform LDS base) + i*16B
#define GL2LDS(g, l) __builtin_amdgcn_global_load_lds( \
    (const __attribute__((address_space(1))) void*)(uintptr_t)(g), \
    (__attribute__((address_space(3))) void*)(l), 16, 0, 0)

// Softmax scales folded into Q at QKV-epilogue time (validated r8):
// long dk=64: (1/8)*log2e ; short/medium dk=128: (1/sqrt(128))*log2e
#define QSC_L  0.18033688011112043f
#define QSC_SM 0.12751744653921766f

// ---------------------------------------------------------------------------
// Batched fp16-MFMA GEMM: C = A @ W^T + bias. BK=64 chunk-major.
// 128xNB tile (NB in {128,64}), 4 waves. batch dim selects {b0,b1,b2}.
// MODE 0: C fp32 + bias. MODE 1: C fp16 + bias.
// MODE 2: QKV split (cols<2048 -> qk fp16 ldc; Q cols (<1024) pre-scaled by
//         softmax scale*log2e; cols>=2048 -> vT transposed).
// MODE 3: C fp16, no bias (Weff prep).
// NB=64 for small-N dispatches (outproj N=1024 was 256 blocks = 1/CU).
// XCD-SWZ removed (r3: +13us on QKV).
// ---------------------------------------------------------------------------
struct GemmBatch {
    const _Float16* A;
    const _Float16* W;
    const float*    bias;
    void*           C;
    void*           C2;
};

template<int MODE, int NB>
__global__ __launch_bounds__(256) void gemm_f16(
    GemmBatch b0, GemmBatch b1, GemmBatch b2, int lda, int ldw, int ldc, int K)
{
    constexpr int NT = NB / 32;          // per-wave n-subtiles
    __shared__ __align__(16) _Float16 As[2*128*32];
    __shared__ __align__(16) _Float16 Bs[2*NB*32];

    const GemmBatch G = (blockIdx.z == 0) ? b0 : ((blockIdx.z == 1) ? b1 : b2);

    const int t = threadIdx.x, lane = t & 63, w = t >> 6;
    const int bm = blockIdx.x * 128, bn = blockIdx.y * NB;
    const int wm = (w >> 1) * 64, wn = (w & 1) * (NB/2);
    const int fr = lane & 15, q8 = (lane >> 4) * 8;
    const int srow = lane >> 2, scol = (lane & 3) * 8;

    f32x4 acc[4][NT] = {};

    const _Float16* Ab = G.A + (size_t)(bm + w*32 + srow) * lda + scol;
    const _Float16* Wb = G.W + (size_t)(bn + w*(NB/4) + srow) * ldw + scol;

    for (int k0 = 0; k0 < K; k0 += 64) {
        __syncthreads();
        #pragma unroll
        for (int kc = 0; kc < 2; kc++) {
            #pragma unroll
            for (int ii = 0; ii < 2; ii++)
                GL2LDS(Ab + (size_t)(ii*16)*lda + k0 + kc*32,
                       As + kc*4096 + w*1024 + ii*512);
            #pragma unroll
            for (int ii = 0; ii < NB/64; ii++)
                GL2LDS(Wb + (size_t)(ii*16)*ldw + k0 + kc*32,
                       Bs + kc*NB*32 + w*(NB/4)*32 + ii*512);
        }
        __syncthreads();
        #pragma unroll
        for (int kc = 0; kc < 2; kc++) {
            half8_t af[4], bf[NT];
            #pragma unroll
            for (int mt = 0; mt < 4; mt++)
                af[mt] = *(const half8_t*)&As[kc*4096 + (wm + mt*16 + fr)*32 + q8];
            #pragma unroll
            for (int nt = 0; nt < NT; nt++)
                bf[nt] = *(const half8_t*)&Bs[kc*NB*32 + (wn + nt*16 + fr)*32 + q8];
            #pragma unroll
            for (int mt = 0; mt < 4; mt++)
                #pragma unroll
                for (int nt = 0; nt < NT; nt++)
                    acc[mt][nt] = __builtin_amdgcn_mfma_f32_16x16x32_f16(
                        af[mt], bf[nt], acc[mt][nt], 0, 0, 0);
        }
    }

    const int cl = lane & 15;
    const int rq = (lane >> 4) * 4;

    if (MODE == 2 && bn >= 2048) {
        #pragma unroll
        for (int mt = 0; mt < 4; mt++) {
            int row0 = bm + wm + mt*16 + rq;
            #pragma unroll
            for (int nt = 0; nt < NT; nt++) {
                int gcol = bn + wn + nt*16 + cl;
                float bv = G.bias[gcol];
                half4_t hv = {(_Float16)(acc[mt][nt][0] + bv),
                              (_Float16)(acc[mt][nt][1] + bv),
                              (_Float16)(acc[mt][nt][2] + bv),
                              (_Float16)(acc[mt][nt][3] + bv)};
                *(half4_t*)((_Float16*)G.C2 + (size_t)(gcol - 2048) * M_ + row0) = hv;
            }
        }
        return;
    }

    // Q pre-scale (MODE 2, cols < 1024): batch z=2 is long (dk=64).
    const float qsc = (MODE == 2 && bn < 1024)
                      ? ((blockIdx.z == 2) ? QSC_L : QSC_SM) : 1.0f;

    #pragma unroll
    for (int mt = 0; mt < 4; mt++) {
        #pragma unroll
        for (int r = 0; r < 4; r++) {
            size_t grow = (size_t)(bm + wm + mt*16 + rq + r);
            #pragma unroll
            for (int nt = 0; nt < NT; nt++) {
                int gcol = bn + wn + nt*16 + cl;
                float v = acc[mt][nt][r] + ((MODE == 3) ? 0.f : G.bias[gcol]);
                if (MODE == 2) v *= qsc;
                if (MODE == 0)
                    ((float*)G.C)[grow * ldc + gcol] = v;
                else
                    ((_Float16*)G.C)[grow * ldc + gcol] = (_Float16)v;
            }
        }
    }
}

// ---------------------------------------------------------------------------
// Fused fp32 -> fp16 cast (5 tensors: x, w_in x3, w_comb).
// ---------------------------------------------------------------------------
struct CastArgs {
    const float* s[5];
    _Float16*    d[5];
    int          nb[5];
};

__global__ __launch_bounds__(256) void cast_all(CastArgs a)
{
    int off = blockIdx.x;
    int seg = 0;
    while (seg < 4 && off >= a.nb[seg]) { off -= a.nb[seg]; seg++; }
    int i = off * 256 + threadIdx.x;
    float4 v = ((const float4*)a.s[seg])[i];
    half4_t h = {(_Float16)v.x, (_Float16)v.y, (_Float16)v.z, (_Float16)v.w};
    ((half4_t*)a.d[seg])[i] = h;
}

// ---------------------------------------------------------------------------
// Transposing cast for wo_* : in fp32 [1024 d][1024 e] -> out fp16 [e][d].
// ---------------------------------------------------------------------------
__global__ __launch_bounds__(256) void transpose_cast_wo(
    const float* s0, const float* s1, const float* s2,
    _Float16* d0, _Float16* d1, _Float16* d2)
{
    __shared__ float T[64][68];
    const float* src = blockIdx.z == 0 ? s0 : (blockIdx.z == 1 ? s1 : s2);
    _Float16*    dst = blockIdx.z == 0 ? d0 : (blockIdx.z == 1 ? d1 : d2);
    const int db = blockIdx.x * 64;
    const int eb = blockIdx.y * 64;
    const int r = threadIdx.x >> 4;
    const int c = (threadIdx.x & 15) * 4;

    #pragma unroll
    for (int rr = 0; rr < 4; rr++) {
        float4 v = *(const float4*)&src[(size_t)(db + rr*16 + r)*1024 + eb + c];
        T[rr*16 + r][c+0] = v.x; T[rr*16 + r][c+1] = v.y;
        T[rr*16 + r][c+2] = v.z; T[rr*16 + r][c+3] = v.w;
    }
    __syncthreads();
    #pragma unroll
    for (int rr = 0; rr < 4; rr++) {
        int e = rr*16 + r;
        half4_t hv = {(_Float16)T[c+0][e], (_Float16)T[c+1][e],
                      (_Float16)T[c+2][e], (_Float16)T[c+3][e]};
        *(half4_t*)&dst[(size_t)(eb + e)*1024 + db + c] = hv;
    }
}

// ---------------------------------------------------------------------------
// beff[n] = b_comb[n] + sum_d bo_s[d] Wc[n][d] + bo_m[d] Wc[n][1024+d] + bo_l[d] Wc[n][2048+d]
// ---------------------------------------------------------------------------
__global__ __launch_bounds__(256) void beff_kernel(
    const float* __restrict__ w_comb, const float* __restrict__ b_comb,
    const float* __restrict__ bo_s, const float* __restrict__ bo_m,
    const float* __restrict__ bo_l, float* __restrict__ beff)
{
    __shared__ float red[4];
    const int n = blockIdx.x, t = threadIdx.x;
    float s = 0.f;
    for (int d = t; d < 1024; d += 256)
        s += w_comb[(size_t)n*3072 + d]        * bo_s[d]
           + w_comb[(size_t)n*3072 + 1024 + d] * bo_m[d]
           + w_comb[(size_t)n*3072 + 2048 + d] * bo_l[d];
    #pragma unroll
    for (int m = 32; m >= 1; m >>= 1) s += __shfl_xor(s, m);
    if ((t & 63) == 0) red[t >> 6] = s;
    __syncthreads();
    if (t == 0) beff[n] = b_comb[n] + red[0] + red[1] + red[2] + red[3];
}

// ---------------------------------------------------------------------------
// Flash attention body — r6-proven 4-wave single-buffered structure.
// (r4 dbuf: occupancy regression. r5 setprio: regression. r7/r8 8-wave:
// VGPR 40 + scratch spill explosion, FETCH/WRITE 224/119MB — reverted.)
// LDS partition (halfs): Ks [0, DK*BJ) | Vs [DK*BJ, 2*DK*BJ) | Ps (P patch).
// DK*BJ = 8192 both instantiations -> 37.9KB -> 4 blocks/CU; implicit
// inter-block overlap hides the stage drain (m114 mechanism).
// T2 swizzle (r2): XOR 16B slot with (row>>1)&3 via pre-swizzled global
// source + swizzled read (BANK_CONFLICT 2.2e7 -> 4.9e6).
// Q PRE-SCALED by softmax-scale*log2e at QKV epilogue -> exp2f(st) direct
// (saves one v_mul per exp2; numerics validated r8, absmax unchanged).
// ---------------------------------------------------------------------------
template<int DK, int BJ, bool LOUT>
__device__ __forceinline__ void flash_body(
    _Float16* lds, float* Lw,
    const _Float16* __restrict__ qk, const _Float16* __restrict__ vT,
    _Float16* __restrict__ ctx, float* __restrict__ lout,
    int window, int b, int h, int qblk, int H)
{
    constexpr int KS  = DK / 32;     // k-chunks
    constexpr int DT  = DK / 16;     // PV d-tiles
    constexpr int JT  = BJ / 16;     // j-subtiles per round
    constexpr int JC  = BJ / 32;     // j-chunks per round (PV kc count)
    constexpr int LDP = 40;

    _Float16* Ks = lds;
    _Float16* Vs = lds + DK*BJ;
    _Float16* Ps = lds + 2*DK*BJ;

    const int t = threadIdx.x, lane = t & 63, w = t >> 6;
    const int fr = lane & 15, g = lane >> 4, k8 = g * 8;
    // swizzled LDS fragment slot: slot g holds global chunk g^((row>>1)&3)
    const int k8s = (g ^ ((fr >> 1) & 3)) * 8;
    const int blkQ = qblk * 64;
    const int qlo  = blkQ + w * 16;

    _Float16* PsW = Ps + w * 16 * LDP;
    const int srow = lane >> 2;
    // stage-side inverse swizzle of the global source chunk
    const int ssw  = ((lane & 3) ^ ((srow >> 1) & 3)) * 8;

    half8_t qf[KS];
    #pragma unroll
    for (int kk = 0; kk < KS; kk++)
        qf[kk] = *(const half8_t*)&qk[(size_t)(b*S_ + qlo + fr)*2048 + h*DK + kk*32 + k8];

    f32x4 O[DT] = {};
    float lsum = 0.f;

    for (int j0 = 0; j0 < S_; j0 += BJ) {
        if (window >= 0 && j0 + BJ - 1 < blkQ - window) continue;
        __syncthreads();

        // stage K: [kchunk][BJ rows][32]; wave w rows w*(BJ/4)+ii*16+srow
        #pragma unroll
        for (int kk = 0; kk < KS; kk++)
            #pragma unroll
            for (int ii = 0; ii < BJ/64; ii++)
                GL2LDS(&qk[(size_t)(b*S_ + j0 + w*(BJ/4) + ii*16 + srow)*2048
                           + 1024 + h*DK + kk*32 + ssw],
                       &Ks[kk*BJ*32 + w*(BJ/4)*32 + ii*512]);
        // stage vT: [jchunk][DK rows][32]; wave w d-rows w*(DK/4)+ii*16+srow
        #pragma unroll
        for (int jc = 0; jc < JC; jc++)
            #pragma unroll
            for (int ii = 0; ii < DK/64; ii++)
                GL2LDS(&vT[(size_t)(h*DK + w*(DK/4) + ii*16 + srow)*M_
                           + b*S_ + j0 + jc*32 + ssw],
                       &Vs[jc*DK*32 + w*(DK/4)*32 + ii*512]);
        __syncthreads();

        f32x4 st[JT];
        #pragma unroll
        for (int jt = 0; jt < JT; jt++) {
            f32x4 s = {};
            #pragma unroll
            for (int kk = 0; kk < KS; kk++) {
                half8_t kf = *(const half8_t*)&Ks[kk*BJ*32 + (jt*16 + fr)*32 + k8s];
                s = __builtin_amdgcn_mfma_f32_16x16x32_f16(kf, qf[kk], s, 0, 0, 0);
            }
            st[jt] = s;
        }

        const bool full = (window < 0) || (j0 >= qlo + 15 - window);
        #pragma unroll
        for (int kc = 0; kc < JC; kc++) {
            #pragma unroll
            for (int jh = 0; jh < 2; jh++) {
                int jt = kc*2 + jh;
                float p[4];
                #pragma unroll
                for (int r = 0; r < 4; r++) {
                    float pv = exp2f(st[jt][r]);
                    if (!full) {
                        int jg = j0 + jt*16 + g*4 + r;
                        if (jg < (qlo + fr) - window) pv = 0.f;
                    }
                    p[r] = pv;
                    lsum += pv;
                }
                half4_t ph = {(_Float16)p[0], (_Float16)p[1],
                              (_Float16)p[2], (_Float16)p[3]};
                *(half4_t*)&PsW[fr*LDP + jh*16 + g*4] = ph;
            }
            // same-wave DS ordering: write -> read -> next overwrite is safe
            half8_t pf = *(const half8_t*)&PsW[fr*LDP + k8];
            #pragma unroll
            for (int dt = 0; dt < DT; dt++) {
                half8_t vf = *(const half8_t*)&Vs[kc*DK*32 + (dt*16 + fr)*32 + k8s];
                O[dt] = __builtin_amdgcn_mfma_f32_16x16x32_f16(pf, vf, O[dt], 0, 0, 0);
            }
        }
    }

    lsum += __shfl_xor(lsum, 16);
    lsum += __shfl_xor(lsum, 32);
    if (g == 0) Lw[w*16 + fr] = lsum;
    float linv[4];
    #pragma unroll
    for (int r = 0; r < 4; r++)
        linv[r] = 1.f / Lw[w*16 + g*4 + r];

    if (LOUT && g == 0)
        lout[(size_t)(b*H + h)*S_ + qlo + fr] = lsum;

    #pragma unroll
    for (int r = 0; r < 4; r++) {
        _Float16* cp = ctx + (size_t)(b*S_ + qlo + g*4 + r)*CTXLD + h*DK;
        #pragma unroll
        for (int dt = 0; dt < DT; dt++)
            cp[dt*16 + fr] = (_Float16)(O[dt][r] * linv[r]);
    }
}

// ---------------------------------------------------------------------------
// Mega flash: all three branches in one 2048-block dispatch.
// T1 XCD remap (r3): bid = (hw&7)*256 + hw>>3 (bijective). Each XCD owns
// 256 logically-consecutive blocks = aligned K/V-sharing groups (~2MB < 4MB
// L2). FETCH 364MB -> 44MB measured. Long on XCDs 0-3, s/m on 4-7.
// s/m qblk = r&31 (heavy qblk=0 first within each group).
// ---------------------------------------------------------------------------
__global__ __launch_bounds__(256, 4) void flash_mega(
    const _Float16* __restrict__ qk_s, const _Float16* __restrict__ qk_m,
    const _Float16* __restrict__ qk_l,
    const _Float16* __restrict__ vT_s, const _Float16* __restrict__ vT_m,
    const _Float16* __restrict__ vT_l,
    _Float16* __restrict__ ctxall, float* __restrict__ lbuf)
{
    __shared__ __align__(16) _Float16 lds[18944];
    __shared__ float Lw[64];

    const int hwb = blockIdx.x;
    const int bid = (hwb & 7) * 256 + (hwb >> 3);
    if (bid < 1024) {
        int qblk = bid & 31, h = (bid >> 5) & 15, b = bid >> 9;
        flash_body<64, 128, true>(lds, Lw, qk_l, vT_l, ctxall + 2048, lbuf,
                                  -1, b, h, qblk, 16);
    } else {
        int r = bid - 1024;
        int qblk = r & 31;              // heavy (qblk=0) first within group
        int h = (r >> 5) & 7;
        int z = r >> 8;                 // 0..3 = branch*2 + batch
        int br = z >> 1, b = z & 1;
        flash_body<128, 64, false>(lds, Lw, br ? qk_m : qk_s, br ? vT_m : vT_s,
                                   ctxall + (br ? 1024 : 0), nullptr,
                                   br ? 30 : 10, b, h, qblk, 8);
    }
}

// ---------------------------------------------------------------------------
// Head-averaged long-branch attention probabilities (2 heads per barrier).
// Same T2 swizzle as flash_body. Q pre-scaled -> no c1 multiply.
// ---------------------------------------------------------------------------
__global__ __launch_bounds__(256, 4) void attn_mean3(
    const _Float16* __restrict__ qk,
    const float* __restrict__ lbuf,
    float* __restrict__ attn)
{
    __shared__ __align__(16) _Float16 Ks[2 * 2 * 128 * 32];

    const int t = threadIdx.x, lane = t & 63, w = t >> 6;
    const int fr = lane & 15, g = lane >> 4, k8 = g * 8;
    const int k8s = (g ^ ((fr >> 1) & 3)) * 8;
    const int j0 = blockIdx.x * 128;
    const int irow = blockIdx.y * 64 + w * 16;
    const int b = blockIdx.z;
    const int srow = lane >> 2;
    const int ssw  = ((lane & 3) ^ ((srow >> 1) & 3)) * 8;

    f32x4 acc[8] = {};

    for (int hp = 0; hp < 16; hp += 2) {
        __syncthreads();
        #pragma unroll
        for (int hh = 0; hh < 2; hh++)
            #pragma unroll
            for (int kk = 0; kk < 2; kk++)
                #pragma unroll
                for (int ii = 0; ii < 2; ii++)
                    GL2LDS(&qk[(size_t)(b*S_ + j0 + w*32 + ii*16 + srow)*2048
                               + 1024 + (hp+hh)*64 + kk*32 + ssw],
                           &Ks[hh*8192 + kk*4096 + w*1024 + ii*512]);
        __syncthreads();

        #pragma unroll
        for (int hh = 0; hh < 2; hh++) {
            const int h = hp + hh;
            half8_t af[2];
            #pragma unroll
            for (int kk = 0; kk < 2; kk++)
                af[kk] = *(const half8_t*)
                    &qk[(size_t)(b*S_ + irow + fr)*2048 + h*64 + kk*32 + k8];

            float lg[4];
            #pragma unroll
            for (int r = 0; r < 4; r++)
                lg[r] = __log2f(lbuf[(size_t)(b*16 + h)*S_ + irow + g*4 + r]) + 4.0f;

            #pragma unroll
            for (int nt = 0; nt < 8; nt++) {
                f32x4 s = {};
                #pragma unroll
                for (int kk = 0; kk < 2; kk++) {
                    half8_t bf = *(const half8_t*)
                        &Ks[hh*8192 + kk*4096 + (nt*16 + fr)*32 + k8s];
                    s = __builtin_amdgcn_mfma_f32_16x16x32_f16(af[kk], bf, s, 0, 0, 0);
                }
                #pragma unroll
                for (int r = 0; r < 4; r++)
                    acc[nt][r] += exp2f(s[r] - lg[r]);
            }
        }
    }

    #pragma unroll
    for (int r = 0; r < 4; r++) {
        float* p = attn + (size_t)(b*S_ + irow + g*4 + r)*S_ + j0;
        #pragma unroll
        for (int nt = 0; nt < 8; nt++)
            p[nt*16 + fr] = acc[nt][r];
    }
}

// ---------------------------------------------------------------------------
// Residual + LayerNorm
// ---------------------------------------------------------------------------
__global__ __launch_bounds__(256) void ln_residual(
    const float* __restrict__ pre, const float* __restrict__ x,
    const float* __restrict__ gamma, const float* __restrict__ beta,
    float* __restrict__ out)
{
    __shared__ float redS[4], redQ[4];
    const int row = blockIdx.x;
    const int t = threadIdx.x;
    size_t base = (size_t)row * D_ + t * 4;

    float4 v  = *(const float4*)(pre + base);
    float4 xv = *(const float4*)(x + base);
    v.x += xv.x; v.y += xv.y; v.z += xv.z; v.w += xv.w;

    float s = v.x + v.y + v.z + v.w;
    float q = v.x*v.x + v.y*v.y + v.z*v.z + v.w*v.w;
    #pragma unroll
    for (int m = 32; m >= 1; m >>= 1) {
        s += __shfl_xor(s, m);
        q += __shfl_xor(q, m);
    }
    int wave = t >> 6;
    if ((t & 63) == 0) { redS[wave] = s; redQ[wave] = q; }
    __syncthreads();
    s = redS[0] + redS[1] + redS[2] + redS[3];
    q = redQ[0] + redQ[1] + redQ[2] + redQ[3];

    float mean = s * (1.f / D_);
    float var  = q * (1.f / D_) - mean * mean;
    float rstd = rsqrtf(var + 1e-5f);

    float4 g  = *(const float4*)(gamma + t * 4);
    float4 be = *(const float4*)(beta + t * 4);
    float4 o;
    o.x = (v.x - mean) * rstd * g.x + be.x;
    o.y = (v.y - mean) * rstd * g.y + be.y;
    o.z = (v.z - mean) * rstd * g.z + be.z;
    o.w = (v.w - mean) * rstd * g.w + be.w;
    *(float4*)(out + base) = o;
}

// ---------------------------------------------------------------------------
extern "C" void kernel_launch(void* const* d_in, const int* in_sizes, int n_in,
                              void* d_out, int out_size, void* d_ws, size_t ws_size,
                              hipStream_t stream)
{
    (void)in_sizes; (void)n_in; (void)out_size; (void)ws_size;
    const float* x      = (const float*)d_in[0];
    const float* w_in_s = (const float*)d_in[1];
    const float* b_in_s = (const float*)d_in[2];
    const float* wo_s   = (const float*)d_in[3];
    const float* bo_s   = (const float*)d_in[4];
    const float* w_in_m = (const float*)d_in[5];
    const float* b_in_m = (const float*)d_in[6];
    const float* wo_m   = (const float*)d_in[7];
    const float* bo_m   = (const float*)d_in[8];
    const float* w_in_l = (const float*)d_in[9];
    const float* b_in_l = (const float*)d_in[10];
    const float* wo_l   = (const float*)d_in[11];
    const float* bo_l   = (const float*)d_in[12];
    const float* w_comb = (const float*)d_in[13];
    const float* b_comb = (const float*)d_in[14];
    const float* gamma  = (const float*)d_in[15];
    const float* beta   = (const float*)d_in[16];

    float* out    = (float*)d_out;                 // [B,S,D]
    float* attn_o = out + (size_t)M_ * D_;         // [B,S,S]

    // Workspace (byte offsets; total ~132.3 MB <= proven-available 134.5 MB).
    // Alias lifetimes (stream order):
    //   w_comb_h+woT_s [18,26)MB dead after weff gemm -> vT_l (qkv_all writes it after)
    //   qk_m dead after flash_mega -> pre (fused gemm output)
    char* W = (char*)d_ws;
    _Float16* w_in_s_h = (_Float16*)(W);                 //  6MB
    _Float16* w_in_m_h = (_Float16*)(W + 6291456);       //  6MB
    _Float16* w_in_l_h = (_Float16*)(W + 12582912);      //  6MB
    _Float16* w_comb_h = (_Float16*)(W + 18874368);      //  6MB (-> vT_l)
    _Float16* woT_s    = (_Float16*)(W + 25165824);      //  2MB (-> vT_l tail)
    _Float16* woT_m    = (_Float16*)(W + 27262976);      //  2MB
    _Float16* woT_l    = (_Float16*)(W + 29360128);      //  2MB
    _Float16* weff     = (_Float16*)(W + 31457280);      //  6MB
    _Float16* qk_s     = (_Float16*)(W + 37748736);      // 16MB
    _Float16* qk_m     = (_Float16*)(W + 54525952);      // 16MB (-> pre fp32)
    _Float16* qk_l     = (_Float16*)(W + 71303168);      // 16MB
    _Float16* vT_s     = (_Float16*)(W + 88080384);      //  8MB
    _Float16* vT_m     = (_Float16*)(W + 96468992);      //  8MB
    _Float16* ctxall   = (_Float16*)(W + 104857600);     // 24MB [4096][3072]
    _Float16* x_h      = (_Float16*)(W + 130023424);     //  8MB
    float*    lbuf     = (float*)   (W + 138412032);     // 256KB
    float*    beff     = (float*)   (W + 138674432);     //  4KB
    _Float16* vT_l     = w_comb_h;                       // 8MB alias (see above)
    float*    pre      = (float*)qk_m;

    dim3 blk(256);
    GemmBatch nil = { nullptr, nullptr, nullptr, nullptr, nullptr };

    // ---- casts: x, w_in x3, w_comb ----
    CastArgs ca;
    ca.s[0]=x;      ca.d[0]=x_h;      ca.nb[0]=4096;
    ca.s[1]=w_in_s; ca.d[1]=w_in_s_h; ca.nb[1]=3072;
    ca.s[2]=w_in_m; ca.d[2]=w_in_m_h; ca.nb[2]=3072;
    ca.s[3]=w_in_l; ca.d[3]=w_in_l_h; ca.nb[3]=3072;
    ca.s[4]=w_comb; ca.d[4]=w_comb_h; ca.nb[4]=3072;
    cast_all<<<dim3(16384), blk, 0, stream>>>(ca);

    // ---- transpose-cast wo_* -> woT_* ----
    transpose_cast_wo<<<dim3(16, 16, 3), blk, 0, stream>>>(
        wo_s, wo_m, wo_l, woT_s, woT_m, woT_l);

    // ---- Weff_b = Wc_b @ wo_b (fp16, no bias); NB=64 -> 384 blocks ----
    GemmBatch we0 = { w_comb_h + 0,    woT_s, nullptr, weff + 0,    nullptr };
    GemmBatch we1 = { w_comb_h + 1024, woT_m, nullptr, weff + 1024, nullptr };
    GemmBatch we2 = { w_comb_h + 2048, woT_l, nullptr, weff + 2048, nullptr };
    gemm_f16<3, 64><<<dim3(8, 16, 3), blk, 0, stream>>>(we0, we1, we2, 3072, 1024, 3072, 1024);

    // ---- beff = b_comb + Wc . bo_cat ----
    beff_kernel<<<dim3(1024), blk, 0, stream>>>(w_comb, b_comb, bo_s, bo_m, bo_l, beff);

    // ---- all three QKV projections in one dispatch (w_comb_h now dead -> vT_l) ----
    GemmBatch qs = { x_h, w_in_s_h, b_in_s, qk_s, vT_s };
    GemmBatch qm = { x_h, w_in_m_h, b_in_m, qk_m, vT_m };
    GemmBatch ql = { x_h, w_in_l_h, b_in_l, qk_l, vT_l };
    gemm_f16<2, 128><<<dim3(M_/128, 3072/128, 3), blk, 0, stream>>>(qs, qm, ql, D_, D_, 2048, D_);

    // ---- mega flash: long + short + medium in one 2048-block dispatch ----
    flash_mega<<<dim3(2048), blk, 0, stream>>>(
        qk_s, qk_m, qk_l, vT_s, vT_m, vT_l, ctxall, lbuf);

    // ---- head-averaged probabilities ----
    attn_mean3<<<dim3(S_/128, S_/64, B_), blk, 0, stream>>>(qk_l, lbuf, attn_o);

    // ---- fused (outproj+combine): pre = ctxall @ weff^T + beff ----
    // NB=64 -> grid 32x16 = 512 blocks = 2/CU
    GemmBatch fb = { ctxall, weff, beff, pre, nullptr };
    gemm_f16<0, 64><<<dim3(M_/128, 1024/64, 1), blk, 0, stream>>>(fb, nil, nil, 3072, 3072, D_, 3072);

    // ---- residual LayerNorm ----
    ln_residual<<<dim3(M_), blk, 0, stream>>>(pre, x, gamma, beta, out);
}

// Round 10
// 517.723 us; speedup vs baseline: 1.2297x; 1.0188x over previous
//
#include <hip/hip_runtime.h>
#include <hip/hip_bf16.h>
#include <math.h>

// Problem constants (fixed by reference)
#define B_ 2
#define S_ 2048
#define D_ 1024
#define M_ (B_*S_)      // 4096 rows
#define CTXLD 3072      // fused ctx row stride: [short | medium | long]

typedef _Float16 half8_t __attribute__((ext_vector_type(8)));
typedef _Float16 half4_t __attribute__((ext_vector_type(4)));
typedef float    f32x4  __attribute__((ext_vector_type(4)));

// async global->LDS: per-lane global addr; HW scatters lane i to (uniform LDS base) + i*16B
#define GL2LDS(g, l) __builtin_amdgcn_global_load_lds( \
    (const __attribute__((address_space(1))) void*)(uintptr_t)(g), \
    (__attribute__((address_space(3))) void*)(l), 16, 0, 0)

// Softmax scales folded into Q at QKV-epilogue time (validated r8):
// long dk=64: (1/8)*log2e ; short/medium dk=128: (1/sqrt(128))*log2e
#define QSC_L  0.18033688011112043f
#define QSC_SM 0.12751744653921766f

// ---------------------------------------------------------------------------
// Batched fp16-MFMA GEMM body: C = A @ W^T + bias. BK=64 chunk-major.
// 128xNB tile (NB in {128,64}), 4 waves.
// MODE 0: C fp32 + bias. MODE 1: C fp16 + bias.
// MODE 2: QKV split (cols<2048 -> qk fp16 ldc; Q cols (<1024) pre-scaled by
//         softmax scale*log2e; cols>=2048 -> vT transposed).
// MODE 3: C fp16, no bias (Weff prep).
// NB=64 for small-N dispatches (outproj N=1024 was 256 blocks = 1/CU).
// XCD-SWZ removed (r3: +13us on QKV).
// ---------------------------------------------------------------------------
struct GemmBatch {
    const _Float16* A;
    const _Float16* W;
    const float*    bias;
    void*           C;
    void*           C2;
};

template<int MODE, int NB>
__device__ __forceinline__ void gemm_body(
    _Float16* As, _Float16* Bs, const GemmBatch& G,
    int lda, int ldw, int ldc, int K, int bx, int by, int bz)
{
    constexpr int NT = NB / 32;          // per-wave n-subtiles

    const int t = threadIdx.x, lane = t & 63, w = t >> 6;
    const int bm = bx * 128, bn = by * NB;
    const int wm = (w >> 1) * 64, wn = (w & 1) * (NB/2);
    const int fr = lane & 15, q8 = (lane >> 4) * 8;
    const int srow = lane >> 2, scol = (lane & 3) * 8;

    f32x4 acc[4][NT] = {};

    const _Float16* Ab = G.A + (size_t)(bm + w*32 + srow) * lda + scol;
    const _Float16* Wb = G.W + (size_t)(bn + w*(NB/4) + srow) * ldw + scol;

    for (int k0 = 0; k0 < K; k0 += 64) {
        __syncthreads();
        #pragma unroll
        for (int kc = 0; kc < 2; kc++) {
            #pragma unroll
            for (int ii = 0; ii < 2; ii++)
                GL2LDS(Ab + (size_t)(ii*16)*lda + k0 + kc*32,
                       As + kc*4096 + w*1024 + ii*512);
            #pragma unroll
            for (int ii = 0; ii < NB/64; ii++)
                GL2LDS(Wb + (size_t)(ii*16)*ldw + k0 + kc*32,
                       Bs + kc*NB*32 + w*(NB/4)*32 + ii*512);
        }
        __syncthreads();
        #pragma unroll
        for (int kc = 0; kc < 2; kc++) {
            half8_t af[4], bf[NT];
            #pragma unroll
            for (int mt = 0; mt < 4; mt++)
                af[mt] = *(const half8_t*)&As[kc*4096 + (wm + mt*16 + fr)*32 + q8];
            #pragma unroll
            for (int nt = 0; nt < NT; nt++)
                bf[nt] = *(const half8_t*)&Bs[kc*NB*32 + (wn + nt*16 + fr)*32 + q8];
            #pragma unroll
            for (int mt = 0; mt < 4; mt++)
                #pragma unroll
                for (int nt = 0; nt < NT; nt++)
                    acc[mt][nt] = __builtin_amdgcn_mfma_f32_16x16x32_f16(
                        af[mt], bf[nt], acc[mt][nt], 0, 0, 0);
        }
    }

    const int cl = lane & 15;
    const int rq = (lane >> 4) * 4;

    if (MODE == 2 && bn >= 2048) {
        #pragma unroll
        for (int mt = 0; mt < 4; mt++) {
            int row0 = bm + wm + mt*16 + rq;
            #pragma unroll
            for (int nt = 0; nt < NT; nt++) {
                int gcol = bn + wn + nt*16 + cl;
                float bv = G.bias[gcol];
                half4_t hv = {(_Float16)(acc[mt][nt][0] + bv),
                              (_Float16)(acc[mt][nt][1] + bv),
                              (_Float16)(acc[mt][nt][2] + bv),
                              (_Float16)(acc[mt][nt][3] + bv)};
                *(half4_t*)((_Float16*)G.C2 + (size_t)(gcol - 2048) * M_ + row0) = hv;
            }
        }
        return;
    }

    // Q pre-scale (MODE 2, cols < 1024): batch z=2 is long (dk=64).
    const float qsc = (MODE == 2 && bn < 1024)
                      ? ((bz == 2) ? QSC_L : QSC_SM) : 1.0f;

    #pragma unroll
    for (int mt = 0; mt < 4; mt++) {
        #pragma unroll
        for (int r = 0; r < 4; r++) {
            size_t grow = (size_t)(bm + wm + mt*16 + rq + r);
            #pragma unroll
            for (int nt = 0; nt < NT; nt++) {
                int gcol = bn + wn + nt*16 + cl;
                float v = acc[mt][nt][r] + ((MODE == 3) ? 0.f : G.bias[gcol]);
                if (MODE == 2) v *= qsc;
                if (MODE == 0)
                    ((float*)G.C)[grow * ldc + gcol] = v;
                else
                    ((_Float16*)G.C)[grow * ldc + gcol] = (_Float16)v;
            }
        }
    }
}

template<int MODE, int NB>
__global__ __launch_bounds__(256) void gemm_f16(
    GemmBatch b0, GemmBatch b1, GemmBatch b2, int lda, int ldw, int ldc, int K)
{
    __shared__ __align__(16) _Float16 As[2*128*32];
    __shared__ __align__(16) _Float16 Bs[2*NB*32];
    const GemmBatch G = (blockIdx.z == 0) ? b0 : ((blockIdx.z == 1) ? b1 : b2);
    gemm_body<MODE, NB>(As, Bs, G, lda, ldw, ldc, K,
                        blockIdx.x, blockIdx.y, blockIdx.z);
}

// ---------------------------------------------------------------------------
// Merged prologue (r10): cast_all (16384 blocks) + transpose_cast_wo (768)
// + beff (1024) in ONE 18176-block dispatch. All three depend only on
// kernel inputs; merging hides transpose+beff under the BW-bound cast and
// drops two launch gaps.
// ---------------------------------------------------------------------------
struct CastArgs {
    const float* s[5];
    _Float16*    d[5];
    int          nb[5];
};

__global__ __launch_bounds__(256) void prep_mega(
    CastArgs a,
    const float* wo_s, const float* wo_m, const float* wo_l,
    _Float16* woT_s, _Float16* woT_m, _Float16* woT_l,
    const float* __restrict__ w_comb, const float* __restrict__ b_comb,
    const float* __restrict__ bo_s, const float* __restrict__ bo_m,
    const float* __restrict__ bo_l, float* __restrict__ beff)
{
    __shared__ float T[64][68];
    __shared__ float red[4];
    const int bid = blockIdx.x;

    if (bid < 16384) {
        // ---- fp32->fp16 cast (x, w_in x3, w_comb) ----
        int off = bid;
        int seg = 0;
        while (seg < 4 && off >= a.nb[seg]) { off -= a.nb[seg]; seg++; }
        int i = off * 256 + threadIdx.x;
        float4 v = ((const float4*)a.s[seg])[i];
        half4_t h = {(_Float16)v.x, (_Float16)v.y, (_Float16)v.z, (_Float16)v.w};
        ((half4_t*)a.d[seg])[i] = h;
        return;
    }
    if (bid < 16384 + 768) {
        // ---- transpose-cast wo_* : fp32 [1024][1024] -> fp16 [e][d] ----
        int rr0 = bid - 16384;
        int bz = rr0 >> 8, rem = rr0 & 255;
        int bx = rem & 15, by = rem >> 4;
        const float* src = bz == 0 ? wo_s : (bz == 1 ? wo_m : wo_l);
        _Float16*    dst = bz == 0 ? woT_s : (bz == 1 ? woT_m : woT_l);
        const int db = bx * 64;
        const int eb = by * 64;
        const int r = threadIdx.x >> 4;
        const int c = (threadIdx.x & 15) * 4;

        #pragma unroll
        for (int rr = 0; rr < 4; rr++) {
            float4 v = *(const float4*)&src[(size_t)(db + rr*16 + r)*1024 + eb + c];
            T[rr*16 + r][c+0] = v.x; T[rr*16 + r][c+1] = v.y;
            T[rr*16 + r][c+2] = v.z; T[rr*16 + r][c+3] = v.w;
        }
        __syncthreads();
        #pragma unroll
        for (int rr = 0; rr < 4; rr++) {
            int e = rr*16 + r;
            half4_t hv = {(_Float16)T[c+0][e], (_Float16)T[c+1][e],
                          (_Float16)T[c+2][e], (_Float16)T[c+3][e]};
            *(half4_t*)&dst[(size_t)(eb + e)*1024 + db + c] = hv;
        }
        return;
    }
    // ---- beff[n] = b_comb[n] + Wc[n,:] . [bo_s|bo_m|bo_l] ----
    {
        const int n = bid - (16384 + 768), t = threadIdx.x;
        float s = 0.f;
        for (int d = t; d < 1024; d += 256)
            s += w_comb[(size_t)n*3072 + d]        * bo_s[d]
               + w_comb[(size_t)n*3072 + 1024 + d] * bo_m[d]
               + w_comb[(size_t)n*3072 + 2048 + d] * bo_l[d];
        #pragma unroll
        for (int m = 32; m >= 1; m >>= 1) s += __shfl_xor(s, m);
        if ((t & 63) == 0) red[t >> 6] = s;
        __syncthreads();
        if (t == 0) beff[n] = b_comb[n] + red[0] + red[1] + red[2] + red[3];
    }
}

// ---------------------------------------------------------------------------
// Flash attention body — r6-proven 4-wave single-buffered structure.
// (r4 dbuf: occupancy regression. r5 setprio: regression. r7/r8 8-wave:
// scratch spill explosion — all reverted.)
// LDS partition (halfs): Ks [0, DK*BJ) | Vs [DK*BJ, 2*DK*BJ) | Ps (P patch).
// DK*BJ = 8192 both instantiations -> 37.9KB -> 4 blocks/CU; implicit
// inter-block overlap hides the stage drain (m114 mechanism).
// T2 swizzle (r2): XOR 16B slot with (row>>1)&3 via pre-swizzled global
// source + swizzled read (BANK_CONFLICT 2.2e7 -> 4.9e6).
// Q PRE-SCALED by softmax-scale*log2e at QKV epilogue -> exp2f(st) direct.
// ---------------------------------------------------------------------------
template<int DK, int BJ, bool LOUT>
__device__ __forceinline__ void flash_body(
    _Float16* lds, float* Lw,
    const _Float16* __restrict__ qk, const _Float16* __restrict__ vT,
    _Float16* __restrict__ ctx, float* __restrict__ lout,
    int window, int b, int h, int qblk, int H)
{
    constexpr int KS  = DK / 32;     // k-chunks
    constexpr int DT  = DK / 16;     // PV d-tiles
    constexpr int JT  = BJ / 16;     // j-subtiles per round
    constexpr int JC  = BJ / 32;     // j-chunks per round (PV kc count)
    constexpr int LDP = 40;

    _Float16* Ks = lds;
    _Float16* Vs = lds + DK*BJ;
    _Float16* Ps = lds + 2*DK*BJ;

    const int t = threadIdx.x, lane = t & 63, w = t >> 6;
    const int fr = lane & 15, g = lane >> 4, k8 = g * 8;
    // swizzled LDS fragment slot: slot g holds global chunk g^((row>>1)&3)
    const int k8s = (g ^ ((fr >> 1) & 3)) * 8;
    const int blkQ = qblk * 64;
    const int qlo  = blkQ + w * 16;

    _Float16* PsW = Ps + w * 16 * LDP;
    const int srow = lane >> 2;
    // stage-side inverse swizzle of the global source chunk
    const int ssw  = ((lane & 3) ^ ((srow >> 1) & 3)) * 8;

    half8_t qf[KS];
    #pragma unroll
    for (int kk = 0; kk < KS; kk++)
        qf[kk] = *(const half8_t*)&qk[(size_t)(b*S_ + qlo + fr)*2048 + h*DK + kk*32 + k8];

    f32x4 O[DT] = {};
    float lsum = 0.f;

    for (int j0 = 0; j0 < S_; j0 += BJ) {
        if (window >= 0 && j0 + BJ - 1 < blkQ - window) continue;
        __syncthreads();

        // stage K: [kchunk][BJ rows][32]; wave w rows w*(BJ/4)+ii*16+srow
        #pragma unroll
        for (int kk = 0; kk < KS; kk++)
            #pragma unroll
            for (int ii = 0; ii < BJ/64; ii++)
                GL2LDS(&qk[(size_t)(b*S_ + j0 + w*(BJ/4) + ii*16 + srow)*2048
                           + 1024 + h*DK + kk*32 + ssw],
                       &Ks[kk*BJ*32 + w*(BJ/4)*32 + ii*512]);
        // stage vT: [jchunk][DK rows][32]; wave w d-rows w*(DK/4)+ii*16+srow
        #pragma unroll
        for (int jc = 0; jc < JC; jc++)
            #pragma unroll
            for (int ii = 0; ii < DK/64; ii++)
                GL2LDS(&vT[(size_t)(h*DK + w*(DK/4) + ii*16 + srow)*M_
                           + b*S_ + j0 + jc*32 + ssw],
                       &Vs[jc*DK*32 + w*(DK/4)*32 + ii*512]);
        __syncthreads();

        f32x4 st[JT];
        #pragma unroll
        for (int jt = 0; jt < JT; jt++) {
            f32x4 s = {};
            #pragma unroll
            for (int kk = 0; kk < KS; kk++) {
                half8_t kf = *(const half8_t*)&Ks[kk*BJ*32 + (jt*16 + fr)*32 + k8s];
                s = __builtin_amdgcn_mfma_f32_16x16x32_f16(kf, qf[kk], s, 0, 0, 0);
            }
            st[jt] = s;
        }

        const bool full = (window < 0) || (j0 >= qlo + 15 - window);
        #pragma unroll
        for (int kc = 0; kc < JC; kc++) {
            #pragma unroll
            for (int jh = 0; jh < 2; jh++) {
                int jt = kc*2 + jh;
                float p[4];
                #pragma unroll
                for (int r = 0; r < 4; r++) {
                    float pv = exp2f(st[jt][r]);
                    if (!full) {
                        int jg = j0 + jt*16 + g*4 + r;
                        if (jg < (qlo + fr) - window) pv = 0.f;
                    }
                    p[r] = pv;
                    lsum += pv;
                }
                half4_t ph = {(_Float16)p[0], (_Float16)p[1],
                              (_Float16)p[2], (_Float16)p[3]};
                *(half4_t*)&PsW[fr*LDP + jh*16 + g*4] = ph;
            }
            // same-wave DS ordering: write -> read -> next overwrite is safe
            half8_t pf = *(const half8_t*)&PsW[fr*LDP + k8];
            #pragma unroll
            for (int dt = 0; dt < DT; dt++) {
                half8_t vf = *(const half8_t*)&Vs[kc*DK*32 + (dt*16 + fr)*32 + k8s];
                O[dt] = __builtin_amdgcn_mfma_f32_16x16x32_f16(pf, vf, O[dt], 0, 0, 0);
            }
        }
    }

    lsum += __shfl_xor(lsum, 16);
    lsum += __shfl_xor(lsum, 32);
    if (g == 0) Lw[w*16 + fr] = lsum;
    float linv[4];
    #pragma unroll
    for (int r = 0; r < 4; r++)
        linv[r] = 1.f / Lw[w*16 + g*4 + r];

    if (LOUT && g == 0)
        lout[(size_t)(b*H + h)*S_ + qlo + fr] = lsum;

    #pragma unroll
    for (int r = 0; r < 4; r++) {
        _Float16* cp = ctx + (size_t)(b*S_ + qlo + g*4 + r)*CTXLD + h*DK;
        #pragma unroll
        for (int dt = 0; dt < DT; dt++)
            cp[dt*16 + fr] = (_Float16)(O[dt][r] * linv[r]);
    }
}

// ---------------------------------------------------------------------------
// Mega flash: all three branches in one 2048-block dispatch.
// T1 XCD remap (r3): bid = (hw&7)*256 + hw>>3 (bijective). Each XCD owns
// 256 logically-consecutive blocks = aligned K/V-sharing groups (~2MB < 4MB
// L2). FETCH 364MB -> 44MB measured. Long on XCDs 0-3, s/m on 4-7.
// s/m qblk = r&31 (heavy qblk=0 first within each group).
// ---------------------------------------------------------------------------
__global__ __launch_bounds__(256, 4) void flash_mega(
    const _Float16* __restrict__ qk_s, const _Float16* __restrict__ qk_m,
    const _Float16* __restrict__ qk_l,
    const _Float16* __restrict__ vT_s, const _Float16* __restrict__ vT_m,
    const _Float16* __restrict__ vT_l,
    _Float16* __restrict__ ctxall, float* __restrict__ lbuf)
{
    __shared__ __align__(16) _Float16 lds[18944];
    __shared__ float Lw[64];

    const int hwb = blockIdx.x;
    const int bid = (hwb & 7) * 256 + (hwb >> 3);
    if (bid < 1024) {
        int qblk = bid & 31, h = (bid >> 5) & 15, b = bid >> 9;
        flash_body<64, 128, true>(lds, Lw, qk_l, vT_l, ctxall + 2048, lbuf,
                                  -1, b, h, qblk, 16);
    } else {
        int r = bid - 1024;
        int qblk = r & 31;              // heavy (qblk=0) first within group
        int h = (r >> 5) & 7;
        int z = r >> 8;                 // 0..3 = branch*2 + batch
        int br = z >> 1, b = z & 1;
        flash_body<128, 64, false>(lds, Lw, br ? qk_m : qk_s, br ? vT_m : vT_s,
                                   ctxall + (br ? 1024 : 0), nullptr,
                                   br ? 30 : 10, b, h, qblk, 8);
    }
}

// ---------------------------------------------------------------------------
// Head-averaged long-branch attention probabilities body (2 heads/barrier).
// Same T2 swizzle as flash_body. Q pre-scaled -> no c1 multiply.
// ---------------------------------------------------------------------------
__device__ __forceinline__ void attn_mean_body(
    _Float16* Ks,
    const _Float16* __restrict__ qk,
    const float* __restrict__ lbuf,
    float* __restrict__ attn, int bx, int by, int b)
{
    const int t = threadIdx.x, lane = t & 63, w = t >> 6;
    const int fr = lane & 15, g = lane >> 4, k8 = g * 8;
    const int k8s = (g ^ ((fr >> 1) & 3)) * 8;
    const int j0 = bx * 128;
    const int irow = by * 64 + w * 16;
    const int srow = lane >> 2;
    const int ssw  = ((lane & 3) ^ ((srow >> 1) & 3)) * 8;

    f32x4 acc[8] = {};

    for (int hp = 0; hp < 16; hp += 2) {
        __syncthreads();
        #pragma unroll
        for (int hh = 0; hh < 2; hh++)
            #pragma unroll
            for (int kk = 0; kk < 2; kk++)
                #pragma unroll
                for (int ii = 0; ii < 2; ii++)
                    GL2LDS(&qk[(size_t)(b*S_ + j0 + w*32 + ii*16 + srow)*2048
                               + 1024 + (hp+hh)*64 + kk*32 + ssw],
                           &Ks[hh*8192 + kk*4096 + w*1024 + ii*512]);
        __syncthreads();

        #pragma unroll
        for (int hh = 0; hh < 2; hh++) {
            const int h = hp + hh;
            half8_t af[2];
            #pragma unroll
            for (int kk = 0; kk < 2; kk++)
                af[kk] = *(const half8_t*)
                    &qk[(size_t)(b*S_ + irow + fr)*2048 + h*64 + kk*32 + k8];

            float lg[4];
            #pragma unroll
            for (int r = 0; r < 4; r++)
                lg[r] = __log2f(lbuf[(size_t)(b*16 + h)*S_ + irow + g*4 + r]) + 4.0f;

            #pragma unroll
            for (int nt = 0; nt < 8; nt++) {
                f32x4 s = {};
                #pragma unroll
                for (int kk = 0; kk < 2; kk++) {
                    half8_t bf = *(const half8_t*)
                        &Ks[hh*8192 + kk*4096 + (nt*16 + fr)*32 + k8s];
                    s = __builtin_amdgcn_mfma_f32_16x16x32_f16(af[kk], bf, s, 0, 0, 0);
                }
                #pragma unroll
                for (int r = 0; r < 4; r++)
                    acc[nt][r] += exp2f(s[r] - lg[r]);
            }
        }
    }

    #pragma unroll
    for (int r = 0; r < 4; r++) {
        float* p = attn + (size_t)(b*S_ + irow + g*4 + r)*S_ + j0;
        #pragma unroll
        for (int nt = 0; nt < 8; nt++)
            p[nt*16 + fr] = acc[nt][r];
    }
}

// ---------------------------------------------------------------------------
// Merged tail (r10): outproj GEMM (512 blocks, first) + attn_mean (1024
// blocks) in ONE dispatch. The two are mutually independent (attn reads
// qk_l + lbuf; outproj reads ctxall/weff/beff, writes pre = aliased dead
// qk_m) but were serialized (~85us) — merged they overlap.
// LDS: one 32KB buffer; outproj uses [0,12288) halfs as As|Bs.
// launch_bounds(256,4) caps VGPR at 128: both paths ~70-85 naturally.
// ---------------------------------------------------------------------------
__global__ __launch_bounds__(256, 4) void tail_mega(
    GemmBatch fb, const _Float16* __restrict__ qk_l,
    const float* __restrict__ lbuf, float* __restrict__ attn_o)
{
    __shared__ __align__(16) _Float16 lds[16384];

    const int bid = blockIdx.x;
    if (bid < 512) {
        // outproj: pre = ctxall @ weff^T + beff ; MODE0, NB=64, grid 32x16
        gemm_body<0, 64>(lds, lds + 8192, fb,
                         3072, 3072, D_, 3072, bid & 31, bid >> 5, 0);
    } else {
        int r = bid - 512;
        attn_mean_body(lds, qk_l, lbuf, attn_o,
                       r & 15, (r >> 4) & 31, r >> 9);
    }
}

// ---------------------------------------------------------------------------
// Residual + LayerNorm
// ---------------------------------------------------------------------------
__global__ __launch_bounds__(256) void ln_residual(
    const float* __restrict__ pre, const float* __restrict__ x,
    const float* __restrict__ gamma, const float* __restrict__ beta,
    float* __restrict__ out)
{
    __shared__ float redS[4], redQ[4];
    const int row = blockIdx.x;
    const int t = threadIdx.x;
    size_t base = (size_t)row * D_ + t * 4;

    float4 v  = *(const float4*)(pre + base);
    float4 xv = *(const float4*)(x + base);
    v.x += xv.x; v.y += xv.y; v.z += xv.z; v.w += xv.w;

    float s = v.x + v.y + v.z + v.w;
    float q = v.x*v.x + v.y*v.y + v.z*v.z + v.w*v.w;
    #pragma unroll
    for (int m = 32; m >= 1; m >>= 1) {
        s += __shfl_xor(s, m);
        q += __shfl_xor(q, m);
    }
    int wave = t >> 6;
    if ((t & 63) == 0) { redS[wave] = s; redQ[wave] = q; }
    __syncthreads();
    s = redS[0] + redS[1] + redS[2] + redS[3];
    q = redQ[0] + redQ[1] + redQ[2] + redQ[3];

    float mean = s * (1.f / D_);
    float var  = q * (1.f / D_) - mean * mean;
    float rstd = rsqrtf(var + 1e-5f);

    float4 g  = *(const float4*)(gamma + t * 4);
    float4 be = *(const float4*)(beta + t * 4);
    float4 o;
    o.x = (v.x - mean) * rstd * g.x + be.x;
    o.y = (v.y - mean) * rstd * g.y + be.y;
    o.z = (v.z - mean) * rstd * g.z + be.z;
    o.w = (v.w - mean) * rstd * g.w + be.w;
    *(float4*)(out + base) = o;
}

// ---------------------------------------------------------------------------
extern "C" void kernel_launch(void* const* d_in, const int* in_sizes, int n_in,
                              void* d_out, int out_size, void* d_ws, size_t ws_size,
                              hipStream_t stream)
{
    (void)in_sizes; (void)n_in; (void)out_size; (void)ws_size;
    const float* x      = (const float*)d_in[0];
    const float* w_in_s = (const float*)d_in[1];
    const float* b_in_s = (const float*)d_in[2];
    const float* wo_s   = (const float*)d_in[3];
    const float* bo_s   = (const float*)d_in[4];
    const float* w_in_m = (const float*)d_in[5];
    const float* b_in_m = (const float*)d_in[6];
    const float* wo_m   = (const float*)d_in[7];
    const float* bo_m   = (const float*)d_in[8];
    const float* w_in_l = (const float*)d_in[9];
    const float* b_in_l = (const float*)d_in[10];
    const float* wo_l   = (const float*)d_in[11];
    const float* bo_l   = (const float*)d_in[12];
    const float* w_comb = (const float*)d_in[13];
    const float* b_comb = (const float*)d_in[14];
    const float* gamma  = (const float*)d_in[15];
    const float* beta   = (const float*)d_in[16];

    float* out    = (float*)d_out;                 // [B,S,D]
    float* attn_o = out + (size_t)M_ * D_;         // [B,S,S]

    // Workspace (byte offsets; total ~132.3 MB <= proven-available 134.5 MB).
    // Alias lifetimes (stream order):
    //   w_comb_h+woT_s [18,26)MB dead after weff gemm -> vT_l (qkv_all writes it after)
    //   qk_m dead after flash_mega -> pre (tail_mega outproj output)
    char* W = (char*)d_ws;
    _Float16* w_in_s_h = (_Float16*)(W);                 //  6MB
    _Float16* w_in_m_h = (_Float16*)(W + 6291456);       //  6MB
    _Float16* w_in_l_h = (_Float16*)(W + 12582912);      //  6MB
    _Float16* w_comb_h = (_Float16*)(W + 18874368);      //  6MB (-> vT_l)
    _Float16* woT_s    = (_Float16*)(W + 25165824);      //  2MB (-> vT_l tail)
    _Float16* woT_m    = (_Float16*)(W + 27262976);      //  2MB
    _Float16* woT_l    = (_Float16*)(W + 29360128);      //  2MB
    _Float16* weff     = (_Float16*)(W + 31457280);      //  6MB
    _Float16* qk_s     = (_Float16*)(W + 37748736);      // 16MB
    _Float16* qk_m     = (_Float16*)(W + 54525952);      // 16MB (-> pre fp32)
    _Float16* qk_l     = (_Float16*)(W + 71303168);      // 16MB
    _Float16* vT_s     = (_Float16*)(W + 88080384);      //  8MB
    _Float16* vT_m     = (_Float16*)(W + 96468992);      //  8MB
    _Float16* ctxall   = (_Float16*)(W + 104857600);     // 24MB [4096][3072]
    _Float16* x_h      = (_Float16*)(W + 130023424);     //  8MB
    float*    lbuf     = (float*)   (W + 138412032);     // 256KB
    float*    beff     = (float*)   (W + 138674432);     //  4KB
    _Float16* vT_l     = w_comb_h;                       // 8MB alias (see above)
    float*    pre      = (float*)qk_m;

    dim3 blk(256);
    GemmBatch nil = { nullptr, nullptr, nullptr, nullptr, nullptr };

    // ---- merged prologue: casts + transpose-cast + beff ----
    CastArgs ca;
    ca.s[0]=x;      ca.d[0]=x_h;      ca.nb[0]=4096;
    ca.s[1]=w_in_s; ca.d[1]=w_in_s_h; ca.nb[1]=3072;
    ca.s[2]=w_in_m; ca.d[2]=w_in_m_h; ca.nb[2]=3072;
    ca.s[3]=w_in_l; ca.d[3]=w_in_l_h; ca.nb[3]=3072;
    ca.s[4]=w_comb; ca.d[4]=w_comb_h; ca.nb[4]=3072;
    prep_mega<<<dim3(16384 + 768 + 1024), blk, 0, stream>>>(
        ca, wo_s, wo_m, wo_l, woT_s, woT_m, woT_l,
        w_comb, b_comb, bo_s, bo_m, bo_l, beff);

    // ---- Weff_b = Wc_b @ wo_b (fp16, no bias); NB=64 -> 384 blocks ----
    GemmBatch we0 = { w_comb_h + 0,    woT_s, nullptr, weff + 0,    nullptr };
    GemmBatch we1 = { w_comb_h + 1024, woT_m, nullptr, weff + 1024, nullptr };
    GemmBatch we2 = { w_comb_h + 2048, woT_l, nullptr, weff + 2048, nullptr };
    gemm_f16<3, 64><<<dim3(8, 16, 3), blk, 0, stream>>>(we0, we1, we2, 3072, 1024, 3072, 1024);

    // ---- all three QKV projections in one dispatch (w_comb_h now dead -> vT_l) ----
    GemmBatch qs = { x_h, w_in_s_h, b_in_s, qk_s, vT_s };
    GemmBatch qm = { x_h, w_in_m_h, b_in_m, qk_m, vT_m };
    GemmBatch ql = { x_h, w_in_l_h, b_in_l, qk_l, vT_l };
    gemm_f16<2, 128><<<dim3(M_/128, 3072/128, 3), blk, 0, stream>>>(qs, qm, ql, D_, D_, 2048, D_);

    // ---- mega flash: long + short + medium in one 2048-block dispatch ----
    flash_mega<<<dim3(2048), blk, 0, stream>>>(
        qk_s, qk_m, qk_l, vT_s, vT_m, vT_l, ctxall, lbuf);

    // ---- merged tail: outproj (512 blocks) + head-averaged probs (1024) ----
    GemmBatch fb = { ctxall, weff, beff, pre, nullptr };
    tail_mega<<<dim3(512 + 1024), blk, 0, stream>>>(fb, qk_l, lbuf, attn_o);

    // ---- residual LayerNorm ----
    ln_residual<<<dim3(M_), blk, 0, stream>>>(pre, x, gamma, beta, out);
}